// Round 2
// baseline (179.476 us; speedup 1.0000x reference)
//
#include <hip/hip_runtime.h>

// ---------------------------------------------------------------------------
// Fused 5-layer GRU (SEQ=1, h0=0) + FC for MI355X (gfx950).  Round 3b.
//
// R3 change: the inner loop was LDS-pipe-bound — 74 of ~104 LDS wave-ops per
// tile were loop-invariant (32 A-frag ds_read_b128 at stride-64B = 8-way bank
// conflict -> the 2.3e7 SQ_LDS_BANK_CONFLICT, plus 42 broadcast bias reads),
// re-read every tile because __launch_bounds__(512,4) capped VGPRs at 128 and
// the asm memory clobbers blocked hoisting.  Now: __launch_bounds__(256,2),
// all 30 layer A-frags + 2 FC frags + fc_b acc-inits hoisted into registers
// (loaded once per wave straight from global; wA/wF dropped from LDS, LDS
// 56KB -> 12.8KB).  Conversions switched to truncation-split with word
// packing (lo plane absorbs hi truncation error; weight bf16-rne quant error
// ~4e-3 still dominates absmax).
// R3b: fix compile error — clang can't bind non-const refs to ext_vector
// elements; split2 now writes scalar temporaries.
//
// Orientation: C^T = W @ h^T  (A = weight tile [gate][k], B = h^T [k][batch]).
// MFMA C/D layout (16x16x32): col = lane&15 = BATCH, row = q*4+i = gate row.
// ---------------------------------------------------------------------------

typedef __attribute__((ext_vector_type(8))) short bf16x8;
typedef __attribute__((ext_vector_type(4))) float f32x4;
typedef __attribute__((ext_vector_type(4))) unsigned int u32x4;
typedef __attribute__((ext_vector_type(2))) unsigned int u32x2;

#define NLAYER 5
#define HB_ST  40  // hbuf row stride in bf16 elems (80 B rows: 16B-aligned, 2-way-free banks)
#define NWAVES 4
#define BLOCK_T (NWAVES * 64)

__device__ __forceinline__ float fexp2(float x) {
#if __has_builtin(__builtin_amdgcn_exp2f)
    return __builtin_amdgcn_exp2f(x);
#else
    return exp2f(x);
#endif
}
__device__ __forceinline__ float frcp(float x) {
#if __has_builtin(__builtin_amdgcn_rcpf)
    return __builtin_amdgcn_rcpf(x);
#else
    return 1.0f / x;
#endif
}

__device__ __forceinline__ unsigned short bf_rne(float f) {
    union { float f; unsigned u; } v; v.f = f;
    unsigned r = v.u + 0x7fffu + ((v.u >> 16) & 1u);
    return (unsigned short)(r >> 16);
}

// Truncation-based split: f ~= bf16(hi) + bf16(lo), packing two consecutive
// elements into one hi word and one lo word (low short = even element).
// hi = trunc(f) (residual < 2^-7|f| captured exactly by the sub), lo = trunc
// of the residual -> combined rel error < 2^-15, negligible vs 2^-8 weights.
__device__ __forceinline__ void split2(float f0, float f1, unsigned &hi, unsigned &lo) {
    unsigned u0 = __float_as_uint(f0), u1 = __float_as_uint(f1);
    unsigned h0 = u0 & 0xffff0000u, h1 = u1 & 0xffff0000u;
    hi = (u0 >> 16) | h1;                       // v_perm-able
    float r0 = f0 - __uint_as_float(h0);        // exact
    float r1 = f1 - __uint_as_float(h1);        // exact
    lo = (__float_as_uint(r0) >> 16) | (__float_as_uint(r1) & 0xffff0000u);
}

__device__ __forceinline__ f32x4 mfma16(bf16x8 a, bf16x8 b, f32x4 c) {
    return __builtin_amdgcn_mfma_f32_16x16x32_bf16(a, b, c, 0, 0, 0);
}

// h = sigmoid(-az) * tanh(an + sigmoid(ar)*cn)
//   = [ez*(1-en)] / [(1+ez)*(1+en)],  ez=e^{-az}, en=e^{-2(an+r*cn)}
__device__ __forceinline__ float gru_act(float ar, float az, float an, float cn) {
    const float NL2E = -1.4426950408889634f;
    float er = fexp2(ar * NL2E);
    float r  = frcp(1.0f + er);
    float ez = fexp2(az * NL2E);
    float a2 = an + r * cn;
    float en = fexp2(a2 * (2.0f * NL2E));
    float num = ez * (1.0f - en);
    float den = (1.0f + ez) * (1.0f + en);
    return num * frcp(den);
}

struct __align__(16) Lds {
    float bsum[NLAYER * 96];                  // r,z: b_ih+b_hh ; n: b_ih only
    float cn_[NLAYER * 32];                   // b_hh n-gate (multiplied by r)
    unsigned short hbuf[NWAVES * 2 * 16 * HB_ST];  // [wave][plane][batch row][hid]
};

union BU { u32x4 w; bf16x8 v; };

__global__ __launch_bounds__(BLOCK_T, 2) void gru_fused(
    const float* __restrict__ x, const float* __restrict__ w_ih,
    const float* __restrict__ b_ih, const float* __restrict__ b_hh,
    const float* __restrict__ fc_w, const float* __restrict__ fc_b,
    float* __restrict__ out, int nTiles)
{
    __shared__ Lds s;
    const int tid = threadIdx.x;

    // ---- stage biases into LDS (once per block) ----
    for (int i = tid; i < NLAYER * 96; i += BLOCK_T) {
        int c = i % 96;
        s.bsum[i] = b_ih[i] + (c < 64 ? b_hh[i] : 0.0f);
    }
    for (int i = tid; i < NLAYER * 32; i += BLOCK_T) {
        int l = i >> 5, c = i & 31;
        s.cn_[i] = b_hh[l * 96 + 64 + c];
    }
    __syncthreads();

    const int lane = tid & 63;
    const int n0 = lane & 15;     // batch-col (B n-index / C col); A row m
    const int q  = lane >> 4;     // k-group (A/B), row-group (C/D)
    unsigned short* hb  = s.hbuf + (tid >> 6) * (2 * 16 * HB_ST);
    unsigned short* hb2 = hb + 16 * HB_ST;

    // ---- hoist all loop-invariant MFMA operands into registers (once) ----
    // 30 layer A-frags (120 VGPR) + 2 FC frags + 2 fc_b acc-inits, straight
    // from global (one-time, L2-broadcast across waves).
    bf16x8 A[NLAYER][6];
    #pragma unroll
    for (int l = 0; l < NLAYER; ++l) {
        #pragma unroll
        for (int g = 0; g < 6; ++g) {
            const float* p = w_ih + (size_t)((l * 96 + g * 16 + n0) * 32 + q * 8);
            f32x4 wa = *(const f32x4*)p;
            f32x4 wb = *(const f32x4*)(p + 4);
            bf16x8 t;
            t[0] = (short)bf_rne(wa[0]); t[1] = (short)bf_rne(wa[1]);
            t[2] = (short)bf_rne(wa[2]); t[3] = (short)bf_rne(wa[3]);
            t[4] = (short)bf_rne(wb[0]); t[5] = (short)bf_rne(wb[1]);
            t[6] = (short)bf_rne(wb[2]); t[7] = (short)bf_rne(wb[3]);
            A[l][g] = t;
        }
    }
    bf16x8 F0, F1;
    {
        const float* p0 = fc_w + (size_t)(n0 * 32 + q * 8);
        const float* p1 = fc_w + (size_t)((16 + n0) * 32 + q * 8);
        f32x4 a0 = *(const f32x4*)p0, a1 = *(const f32x4*)(p0 + 4);
        f32x4 b0 = *(const f32x4*)p1, b1 = *(const f32x4*)(p1 + 4);
        bf16x8 t0, t1;
        t0[0] = (short)bf_rne(a0[0]); t0[1] = (short)bf_rne(a0[1]);
        t0[2] = (short)bf_rne(a0[2]); t0[3] = (short)bf_rne(a0[3]);
        t0[4] = (short)bf_rne(a1[0]); t0[5] = (short)bf_rne(a1[1]);
        t0[6] = (short)bf_rne(a1[2]); t0[7] = (short)bf_rne(a1[3]);
        t1[0] = (short)bf_rne(b0[0]); t1[1] = (short)bf_rne(b0[1]);
        t1[2] = (short)bf_rne(b0[2]); t1[3] = (short)bf_rne(b0[3]);
        t1[4] = (short)bf_rne(b1[0]); t1[5] = (short)bf_rne(b1[1]);
        t1[6] = (short)bf_rne(b1[2]); t1[7] = (short)bf_rne(b1[3]);
        F0 = t0; F1 = t1;
    }
    f32x4 OB0 = *(const f32x4*)(fc_b + q * 4);
    f32x4 OB1 = *(const f32x4*)(fc_b + 16 + q * 4);

    const int waveId  = (int)((blockIdx.x * (unsigned)BLOCK_T + tid) >> 6);
    const int nWavesG = (int)((gridDim.x * (unsigned)BLOCK_T) >> 6);

    for (int tile = waveId; tile < nTiles; tile += nWavesG) {
        const int rowBase = tile * 16;

        // ---- load x as B-frag: batch = rowBase+n0, k = q*8..q*8+7, split ----
        const float* xp = x + (size_t)(rowBase + n0) * 32 + q * 8;
        f32x4 xa = *(const f32x4*)xp;
        f32x4 xb = *(const f32x4*)(xp + 4);
        BU H, L;
        {
            unsigned th0, tl0, th1, tl1, th2, tl2, th3, tl3;
            split2(xa[0], xa[1], th0, tl0);
            split2(xa[2], xa[3], th1, tl1);
            split2(xb[0], xb[1], th2, tl2);
            split2(xb[2], xb[3], th3, tl3);
            H.w[0] = th0; H.w[1] = th1; H.w[2] = th2; H.w[3] = th3;
            L.w[0] = tl0; L.w[1] = tl1; L.w[2] = tl2; L.w[3] = tl3;
        }
        bf16x8 bHi = H.v, bLo = L.v;

        #pragma unroll
        for (int l = 0; l < NLAYER; ++l) {
            // acc init = bias f32x4 (rows q*4..q*4+3 of each 16-row gate tile)
            const float* bs = s.bsum + l * 96;
            f32x4 cR0 = *(const f32x4*)(bs + 0  + q * 4);
            f32x4 cR1 = *(const f32x4*)(bs + 16 + q * 4);
            f32x4 cZ0 = *(const f32x4*)(bs + 32 + q * 4);
            f32x4 cZ1 = *(const f32x4*)(bs + 48 + q * 4);
            f32x4 cN0 = *(const f32x4*)(bs + 64 + q * 4);
            f32x4 cN1 = *(const f32x4*)(bs + 80 + q * 4);
            f32x4 vc0 = *(const f32x4*)(s.cn_ + l * 32 + 0  + q * 4);
            f32x4 vc1 = *(const f32x4*)(s.cn_ + l * 32 + 16 + q * 4);

            cR0 = mfma16(A[l][0], bLo, cR0); cR0 = mfma16(A[l][0], bHi, cR0);
            cR1 = mfma16(A[l][1], bLo, cR1); cR1 = mfma16(A[l][1], bHi, cR1);
            cZ0 = mfma16(A[l][2], bLo, cZ0); cZ0 = mfma16(A[l][2], bHi, cZ0);
            cZ1 = mfma16(A[l][3], bLo, cZ1); cZ1 = mfma16(A[l][3], bHi, cZ1);
            cN0 = mfma16(A[l][4], bLo, cN0); cN0 = mfma16(A[l][4], bHi, cN0);
            cN1 = mfma16(A[l][5], bLo, cN1); cN1 = mfma16(A[l][5], bHi, cN1);

            // ---- activations: lane holds hid = q*4+i (+16), batch = n0 ----
            float h0v[4], h1v[4];
            #pragma unroll
            for (int i = 0; i < 4; ++i) {
                h0v[i] = gru_act(cR0[i], cZ0[i], cN0[i], vc0[i]);
                h1v[i] = gru_act(cR1[i], cZ1[i], cN1[i], vc1[i]);
            }

            // ---- packed word writes into [batch][hid] buffer (2-way free) ----
            unsigned hw0, hw1, hw2, hw3, lw0, lw1, lw2, lw3;
            split2(h0v[0], h0v[1], hw0, lw0);
            split2(h0v[2], h0v[3], hw1, lw1);
            split2(h1v[0], h1v[1], hw2, lw2);
            split2(h1v[2], h1v[3], hw3, lw3);
            *(u32x2*)(hb  + n0 * HB_ST + 0  + q * 4) = (u32x2){hw0, hw1};
            *(u32x2*)(hb  + n0 * HB_ST + 16 + q * 4) = (u32x2){hw2, hw3};
            *(u32x2*)(hb2 + n0 * HB_ST + 0  + q * 4) = (u32x2){lw0, lw1};
            *(u32x2*)(hb2 + n0 * HB_ST + 16 + q * 4) = (u32x2){lw2, lw3};

            // wave-private buffer: drain writes, then read back as B-frag
            asm volatile("s_waitcnt lgkmcnt(0)" ::: "memory");
            bHi = *(const bf16x8*)(hb  + n0 * HB_ST + q * 8);
            bLo = *(const bf16x8*)(hb2 + n0 * HB_ST + q * 8);
            asm volatile("" ::: "memory");
        }

        // ---- FC: out^T = fc_w @ h5^T + fc_b ----
        f32x4 o0 = OB0, o1 = OB1;
        o0 = mfma16(F0, bLo, o0); o0 = mfma16(F0, bHi, o0);
        o1 = mfma16(F1, bLo, o1); o1 = mfma16(F1, bHi, o1);

        // lane holds out[batch = rowBase+n0][emb = t*16 + q*4 + i]
        float* op = out + (size_t)(rowBase + n0) * 32;
        *(f32x4*)(op + 0  + q * 4) = o0;
        *(f32x4*)(op + 16 + q * 4) = o1;
    }
}

extern "C" void kernel_launch(void* const* d_in, const int* in_sizes, int n_in,
                              void* d_out, int out_size, void* d_ws, size_t ws_size,
                              hipStream_t stream) {
    (void)n_in; (void)d_ws; (void)ws_size; (void)out_size;
    const float* x    = (const float*)d_in[0];
    const float* w_ih = (const float*)d_in[1];
    // d_in[2] = w_hh: unused (h0 == 0, T == 1)
    const float* b_ih = (const float*)d_in[3];
    const float* b_hh = (const float*)d_in[4];
    const float* fc_w = (const float*)d_in[5];
    const float* fc_b = (const float*)d_in[6];
    float* out = (float*)d_out;

    const int batch  = in_sizes[0] / 32;   // 1048576
    const int nTiles = batch / 16;         // 65536

    // 1024 blocks x 256 thr (4 waves): 4096 waves, 16 tiles/wave.
    // VGPR ~200-240 expected -> 2 waves/SIMD; LDS only 12.8 KB/block.
    gru_fused<<<1024, BLOCK_T, 0, stream>>>(x, w_ih, b_ih, b_hh, fc_w, fc_b, out, nTiles);
}

// Round 3
// 143.730 us; speedup vs baseline: 1.2487x; 1.2487x over previous
//
#include <hip/hip_runtime.h>

// ---------------------------------------------------------------------------
// Fused 5-layer GRU (SEQ=1, h0=0) + FC for MI355X (gfx950).  Round 4.
//
// R4: revert R3's register-hoist (compiler gave it 128 VGPR + AGPR/scratch
// shuffling, occupancy 32%->20%, dur 184->215us dispatch).  Keep R2's
// high-occupancy LDS-weight structure and fix the two measured costs:
//  (a) wA/wF rows padded 32->40 bf16 (80B = 5 bank-quads, odd multiplier):
//      A-frag ds_read_b128 quad index = (5*n0+q)%8 -> uniform over all 8
//      quads per half-wave.  R2's stride-32 layout put each half-wave on 4
//      of 8 quads = 8-way conflict = the 1.5e7 conflict cycles isolated by
//      the R2->R3 A/B.
//  (b) gru_act rewritten on float2 ext-vectors so non-trans activation math
//      lowers to v_pk_{fma,mul,add}_f32 (VOP3P) — halves the ~440 VALU
//      cycles/tile of activation arithmetic.  Trans ops (3 exp2 + 2 rcp per
//      h) are the exact-math minimum and unchanged.
//
// Orientation: C^T = W @ h^T  (A = weight tile [gate][k], B = h^T [k][batch]).
// MFMA C/D layout (16x16x32): col = lane&15 = BATCH, row = q*4+i = gate row.
// Precision: split-B (activations as bf16 hi+lo planes, two MFMAs per tile);
// weight bf16-rne quant error (~4e-3) dominates absmax.
// ---------------------------------------------------------------------------

typedef __attribute__((ext_vector_type(8))) short bf16x8;
typedef __attribute__((ext_vector_type(4))) float f32x4;
typedef __attribute__((ext_vector_type(2))) float f32x2;
typedef __attribute__((ext_vector_type(4))) unsigned int u32x4;
typedef __attribute__((ext_vector_type(2))) unsigned int u32x2;

#define NLAYER 5
#define W_ST   40  // weight row stride in bf16 (80 B = 5 bank-quads: conflict-free)
#define HB_ST  40  // hbuf row stride in bf16 elems
#define NT     512 // block threads (8 waves)

__device__ __forceinline__ float fexp2(float x) {
#if __has_builtin(__builtin_amdgcn_exp2f)
    return __builtin_amdgcn_exp2f(x);
#else
    return exp2f(x);
#endif
}
__device__ __forceinline__ float frcp(float x) {
#if __has_builtin(__builtin_amdgcn_rcpf)
    return __builtin_amdgcn_rcpf(x);
#else
    return 1.0f / x;
#endif
}

__device__ __forceinline__ unsigned short bf_rne(float f) {
    union { float f; unsigned u; } v; v.f = f;
    unsigned r = v.u + 0x7fffu + ((v.u >> 16) & 1u);
    return (unsigned short)(r >> 16);
}

// Truncation-based split: f ~= bf16(hi) + bf16(lo), packing two consecutive
// elements into one hi word and one lo word (low short = even element).
// Combined rel error < 2^-15, negligible vs 2^-8 weight quant.
__device__ __forceinline__ void split2(float f0, float f1, unsigned &hi, unsigned &lo) {
    unsigned u0 = __float_as_uint(f0), u1 = __float_as_uint(f1);
    unsigned h0 = u0 & 0xffff0000u, h1 = u1 & 0xffff0000u;
    hi = (u0 >> 16) | h1;
    float r0 = f0 - __uint_as_float(h0);        // exact
    float r1 = f1 - __uint_as_float(h1);        // exact
    lo = (__float_as_uint(r0) >> 16) | (__float_as_uint(r1) & 0xffff0000u);
}

__device__ __forceinline__ f32x4 mfma16(bf16x8 a, bf16x8 b, f32x4 c) {
    return __builtin_amdgcn_mfma_f32_16x16x32_bf16(a, b, c, 0, 0, 0);
}

__device__ __forceinline__ f32x2 mk2(float a, float b) { f32x2 v; v.x = a; v.y = b; return v; }
__device__ __forceinline__ f32x2 exp2v(f32x2 v) { f32x2 r; r.x = fexp2(v.x); r.y = fexp2(v.y); return r; }
__device__ __forceinline__ f32x2 rcpv(f32x2 v)  { f32x2 r; r.x = frcp(v.x);  r.y = frcp(v.y);  return r; }

// h = (1-z)*n = sigmoid(-az) * tanh(an + sigmoid(ar)*cn)
//   = [ez*(1-en)] / [(1+ez)*(1+en)],  ez=e^{-az}, en=e^{-2(an+r*cn)}
// Packed 2-wide: non-trans ops lower to v_pk_* VOP3P.
__device__ __forceinline__ f32x2 gru_act2(f32x2 ar, f32x2 az, f32x2 an, f32x2 cn) {
    const float NL2E = -1.4426950408889634f;
    f32x2 er  = exp2v(ar * NL2E);
    f32x2 ez  = exp2v(az * NL2E);
    f32x2 r   = rcpv(er + 1.0f);
    f32x2 a2  = an + r * cn;
    f32x2 en  = exp2v(a2 * (2.0f * NL2E));
    f32x2 num = ez - ez * en;
    f32x2 den = (ez + 1.0f) * (en + 1.0f);
    return num * rcpv(den);
}

struct __align__(16) Lds {
    unsigned short wA[NLAYER * 96 * W_ST];        // 38400 B  [l][gate-row][k], row stride 40
    unsigned short wF[32 * W_ST];                 //  2560 B  fc_w rows, stride 40
    float bsum[NLAYER * 96];                      //  1920 B  r,z: b_ih+b_hh ; n: b_ih only
    float cn_[NLAYER * 32];                       //   640 B  b_hh n-gate
    float fb_[32];                                //   128 B  fc_b
    unsigned short hbuf[8 * 2 * 16 * HB_ST];      // 20480 B  [wave][plane][batch][hid]
};                                                // total 64128 B -> 2 blocks/CU

union BU { u32x4 w; bf16x8 v; };

__global__ __launch_bounds__(NT, 4) void gru_fused(
    const float* __restrict__ x, const float* __restrict__ w_ih,
    const float* __restrict__ b_ih, const float* __restrict__ b_hh,
    const float* __restrict__ fc_w, const float* __restrict__ fc_b,
    float* __restrict__ out, int nTiles)
{
    __shared__ Lds s;
    const int tid = threadIdx.x;

    // ---- stage weights / biases into LDS (once per block) ----
    for (int i = tid; i < NLAYER * 96 * 32; i += NT) {
        int r = i >> 5, c = i & 31;
        s.wA[r * W_ST + c] = bf_rne(w_ih[i]);
    }
    for (int i = tid; i < 32 * 32; i += NT) {
        int r = i >> 5, c = i & 31;
        s.wF[r * W_ST + c] = bf_rne(fc_w[i]);
    }
    for (int i = tid; i < NLAYER * 96; i += NT) {
        int c = i % 96;
        s.bsum[i] = b_ih[i] + (c < 64 ? b_hh[i] : 0.0f);
    }
    for (int i = tid; i < NLAYER * 32; i += NT) {
        int l = i >> 5, c = i & 31;
        s.cn_[i] = b_hh[l * 96 + 64 + c];
    }
    if (tid < 32) s.fb_[tid] = fc_b[tid];
    __syncthreads();

    const int lane = tid & 63;
    const int n0 = lane & 15;     // batch-col (B n-index / C col); A row m
    const int q  = lane >> 4;     // k-group (A/B), row-group (C/D)
    unsigned short* hb  = s.hbuf + (tid >> 6) * (2 * 16 * HB_ST);
    unsigned short* hb2 = hb + 16 * HB_ST;

    const int waveId  = (int)((blockIdx.x * (unsigned)NT + tid) >> 6);
    const int nWavesG = (int)((gridDim.x * (unsigned)NT) >> 6);

    for (int tile = waveId; tile < nTiles; tile += nWavesG) {
        const int rowBase = tile * 16;

        // ---- load x as B-frag: batch = rowBase+n0, k = q*8..q*8+7, split ----
        const float* xp = x + (size_t)(rowBase + n0) * 32 + q * 8;
        f32x4 xa = *(const f32x4*)xp;
        f32x4 xb = *(const f32x4*)(xp + 4);
        BU H, L;
        {
            unsigned th0, tl0, th1, tl1, th2, tl2, th3, tl3;
            split2(xa[0], xa[1], th0, tl0);
            split2(xa[2], xa[3], th1, tl1);
            split2(xb[0], xb[1], th2, tl2);
            split2(xb[2], xb[3], th3, tl3);
            H.w[0] = th0; H.w[1] = th1; H.w[2] = th2; H.w[3] = th3;
            L.w[0] = tl0; L.w[1] = tl1; L.w[2] = tl2; L.w[3] = tl3;
        }
        bf16x8 bHi = H.v, bLo = L.v;

        #pragma unroll
        for (int l = 0; l < NLAYER; ++l) {
            const unsigned short* wb = s.wA + l * 96 * W_ST;
            bf16x8 a0 = *(const bf16x8*)(wb + (0 * 16 + n0) * W_ST + q * 8);
            bf16x8 a1 = *(const bf16x8*)(wb + (1 * 16 + n0) * W_ST + q * 8);
            bf16x8 a2 = *(const bf16x8*)(wb + (2 * 16 + n0) * W_ST + q * 8);
            bf16x8 a3 = *(const bf16x8*)(wb + (3 * 16 + n0) * W_ST + q * 8);
            bf16x8 a4 = *(const bf16x8*)(wb + (4 * 16 + n0) * W_ST + q * 8);
            bf16x8 a5 = *(const bf16x8*)(wb + (5 * 16 + n0) * W_ST + q * 8);

            // acc init = bias f32x4 (rows q*4..q*4+3 of each 16-row gate tile)
            const float* bs = s.bsum + l * 96;
            f32x4 cR0 = *(const f32x4*)(bs + 0  + q * 4);
            f32x4 cR1 = *(const f32x4*)(bs + 16 + q * 4);
            f32x4 cZ0 = *(const f32x4*)(bs + 32 + q * 4);
            f32x4 cZ1 = *(const f32x4*)(bs + 48 + q * 4);
            f32x4 cN0 = *(const f32x4*)(bs + 64 + q * 4);
            f32x4 cN1 = *(const f32x4*)(bs + 80 + q * 4);
            f32x4 vc0 = *(const f32x4*)(s.cn_ + l * 32 + 0  + q * 4);
            f32x4 vc1 = *(const f32x4*)(s.cn_ + l * 32 + 16 + q * 4);

            cR0 = mfma16(a0, bLo, cR0); cR0 = mfma16(a0, bHi, cR0);
            cR1 = mfma16(a1, bLo, cR1); cR1 = mfma16(a1, bHi, cR1);
            cZ0 = mfma16(a2, bLo, cZ0); cZ0 = mfma16(a2, bHi, cZ0);
            cZ1 = mfma16(a3, bLo, cZ1); cZ1 = mfma16(a3, bHi, cZ1);
            cN0 = mfma16(a4, bLo, cN0); cN0 = mfma16(a4, bHi, cN0);
            cN1 = mfma16(a5, bLo, cN1); cN1 = mfma16(a5, bHi, cN1);

            // ---- activations (packed pairs): hid = q*4+i (+16), batch = n0 ----
            f32x2 hA = gru_act2(mk2(cR0[0], cR0[1]), mk2(cZ0[0], cZ0[1]),
                                mk2(cN0[0], cN0[1]), mk2(vc0[0], vc0[1]));
            f32x2 hB = gru_act2(mk2(cR0[2], cR0[3]), mk2(cZ0[2], cZ0[3]),
                                mk2(cN0[2], cN0[3]), mk2(vc0[2], vc0[3]));
            f32x2 hC = gru_act2(mk2(cR1[0], cR1[1]), mk2(cZ1[0], cZ1[1]),
                                mk2(cN1[0], cN1[1]), mk2(vc1[0], vc1[1]));
            f32x2 hD = gru_act2(mk2(cR1[2], cR1[3]), mk2(cZ1[2], cZ1[3]),
                                mk2(cN1[2], cN1[3]), mk2(vc1[2], vc1[3]));

            // ---- packed word writes into [batch][hid] buffer (conflict-free) ----
            unsigned hw0, hw1, hw2, hw3, lw0, lw1, lw2, lw3;
            split2(hA.x, hA.y, hw0, lw0);
            split2(hB.x, hB.y, hw1, lw1);
            split2(hC.x, hC.y, hw2, lw2);
            split2(hD.x, hD.y, hw3, lw3);
            *(u32x2*)(hb  + n0 * HB_ST + 0  + q * 4) = (u32x2){hw0, hw1};
            *(u32x2*)(hb  + n0 * HB_ST + 16 + q * 4) = (u32x2){hw2, hw3};
            *(u32x2*)(hb2 + n0 * HB_ST + 0  + q * 4) = (u32x2){lw0, lw1};
            *(u32x2*)(hb2 + n0 * HB_ST + 16 + q * 4) = (u32x2){lw2, lw3};

            // wave-private buffer: drain writes, then read back as B-frag
            asm volatile("s_waitcnt lgkmcnt(0)" ::: "memory");
            bHi = *(const bf16x8*)(hb  + n0 * HB_ST + q * 8);
            bLo = *(const bf16x8*)(hb2 + n0 * HB_ST + q * 8);
            asm volatile("" ::: "memory");
        }

        // ---- FC: out^T = fc_w @ h5^T + fc_b ----
        bf16x8 f0 = *(const bf16x8*)(s.wF + (0  + n0) * W_ST + q * 8);
        bf16x8 f1 = *(const bf16x8*)(s.wF + (16 + n0) * W_ST + q * 8);
        f32x4 o0 = *(const f32x4*)(s.fb_ + 0  + q * 4);
        f32x4 o1 = *(const f32x4*)(s.fb_ + 16 + q * 4);
        o0 = mfma16(f0, bLo, o0); o0 = mfma16(f0, bHi, o0);
        o1 = mfma16(f1, bLo, o1); o1 = mfma16(f1, bHi, o1);

        // lane holds out[batch = rowBase+n0][emb = t*16 + q*4 + i]
        float* op = out + (size_t)(rowBase + n0) * 32;
        *(f32x4*)(op + 0  + q * 4) = o0;
        *(f32x4*)(op + 16 + q * 4) = o1;
    }
}

extern "C" void kernel_launch(void* const* d_in, const int* in_sizes, int n_in,
                              void* d_out, int out_size, void* d_ws, size_t ws_size,
                              hipStream_t stream) {
    (void)n_in; (void)d_ws; (void)ws_size; (void)out_size;
    const float* x    = (const float*)d_in[0];
    const float* w_ih = (const float*)d_in[1];
    // d_in[2] = w_hh: unused (h0 == 0, T == 1)
    const float* b_ih = (const float*)d_in[3];
    const float* b_hh = (const float*)d_in[4];
    const float* fc_w = (const float*)d_in[5];
    const float* fc_b = (const float*)d_in[6];
    float* out = (float*)d_out;

    const int batch  = in_sizes[0] / 32;   // 1048576
    const int nTiles = batch / 16;         // 65536

    // 512 blocks x 512 thr: 2 blocks/CU (LDS 64.1 KB), 4096 waves, 16 tiles/wave.
    gru_fused<<<512, NT, 0, stream>>>(x, w_ih, b_ih, b_hh, fc_w, fc_b, out, nTiles);
}